// Round 2
// 140.024 us; speedup vs baseline: 1.0160x; 1.0160x over previous
//
#include <hip/hip_runtime.h>

// Attention S=8192 D=256, scale=1/sqrt(8192)(seq len). Round 8 (fix: pkrtz bitcast):
//  - triple-buffered LDS, staged via global_load_lds dwordx4 (no staging regs,
//    no ds_writes); one __syncthreads per body supplies the vmcnt drain.
//  - QK pipelined one tile ahead: body it = {stage(it+2), QK(it+1), exp2(it)
//    [independent, overlaps QK MFMAs], PV(it)} -> exp2 off the MFMA critical
//    path (T15), s_setprio(1) around the MFMA-dense region (T5).
//  - K8/Vt stored in "LDS-image" layouts written by prep: every K-frag read is
//    ds_read_b128 of a contiguous 1KB wave region (8 b128 vs 16 b64), V same
//    (16 contiguous b128); staging is a verbatim linear copy.
//  - math identical to R7 (fp8 S^T QK, pi-permuted Vt, f16 PV, l via ones-MFMA).

typedef __attribute__((ext_vector_type(4))) float    f32x4;
typedef __attribute__((ext_vector_type(4))) int      i32x4;
typedef __attribute__((ext_vector_type(2))) long     lx2;
typedef __attribute__((ext_vector_type(2))) _Float16 h2;
typedef __attribute__((ext_vector_type(2))) __fp16   h2raw;
typedef __attribute__((ext_vector_type(8))) _Float16 h8;
typedef long  __attribute__((may_alias)) long_a;
typedef lx2   __attribute__((may_alias)) lx2_a;
typedef h8    __attribute__((may_alias)) h8_a;

#define SEQ 8192
#define DIM 256
#define NSPLIT 8
#define KPS (SEQ / NSPLIT)          // 1024 keys per split
#define BN 32                        // keys per tile
#define ITERS (KPS / BN)             // 32
#define BM 128                       // q rows per block = 4 waves x 32

#define KSC (1.4426950408889634f / 90.50966799187808f)   // log2(e)/sqrt(8192)

#define KTILE 8192                   // bytes per 32-key K tile (fp8)
#define VTILE 16384                  // bytes per 32-key V tile (f16)
#define BUFSZ (KTILE + VTILE)

// ---- fused prep ----------------------------------------------------------
// Q8: row-major fp8 (qf loads straight from global).
// K8: per-32-key tile, LDS-image layout: byte(key,c) with c=s*32+qq*8+j goes to
//     chunk=(s>>1)*2+(key>>4), off = chunk*1024 + qq*256 + (key&15)*16 + (s&1)*8 + j
//     -> attn reads chunk at koff=qq*256+l15*16 as one b128 = s-pair.
// Vt: per-tile [qq][d][8 logical keys] f16 (pi-permutation baked in) -> attn
//     reads d-block n at qq*4096 + n*256 + l15*16 as one b128.
__global__ void __launch_bounds__(256)
prep(const float* __restrict__ Q, const float* __restrict__ K,
     const float* __restrict__ V, unsigned char* __restrict__ Q8,
     unsigned char* __restrict__ K8, _Float16* __restrict__ Vt) {
    __shared__ _Float16 tile[32][264];
    int b = blockIdx.x, t = threadIdx.x;

    // Q/K -> fp8 (HW RNE)
    {
        int row = b * 32 + (t >> 3);
        int c0 = (t & 7) * 8;
        const f32x4* q4 = (const f32x4*)Q + (size_t)row * 64 + c0;
        const f32x4* k4 = (const f32x4*)K + (size_t)row * 64 + c0;
        int qo[8], ko[8];
        #pragma unroll
        for (int i = 0; i < 8; ++i) {
            f32x4 q = q4[i], k = k4[i];
            int dq = 0, dk = 0;
            dq = __builtin_amdgcn_cvt_pk_fp8_f32(q.x, q.y, dq, false);
            dq = __builtin_amdgcn_cvt_pk_fp8_f32(q.z, q.w, dq, true);
            dk = __builtin_amdgcn_cvt_pk_fp8_f32(k.x, k.y, dk, false);
            dk = __builtin_amdgcn_cvt_pk_fp8_f32(k.z, k.w, dk, true);
            qo[i] = dq; ko[i] = dk;
        }
        i32x4* qd = (i32x4*)(Q8 + (size_t)row * 256 + (t & 7) * 32);
        qd[0] = *(i32x4*)&qo[0]; qd[1] = *(i32x4*)&qo[4];

        // K8 LDS-image scatter: s=t&7, s16=(s>>1), sp=s&1, half=t>>7, l15=(t>>3)&15
        int s16h = (((t & 7) >> 1) << 1) + (t >> 7);          // s16*2 + half
        long* kdst = (long*)(K8 + (size_t)b * KTILE + (size_t)s16h * 1024
                             + (size_t)((t >> 3) & 15) * 16 + (size_t)(t & 1) * 8);
        #pragma unroll
        for (int q = 0; q < 4; ++q) kdst[q * 32] = *(const long*)&ko[2 * q];
    }

    // V tile b (physical keys b*32..+31) -> f16, logical slot 8a+j holds
    // physical key pi(8a+j) = 4a+j (j<4) / 16+4a+j-4 (j>=4)
    #pragma unroll
    for (int i = 0; i < 8; ++i) {
        int c = t + i * 256;
        int row = c >> 6, col = c & 63;
        f32x4 v = ((const f32x4*)V)[(size_t)(b * 32 + row) * 64 + col];
        tile[row][col * 4 + 0] = (_Float16)v.x;
        tile[row][col * 4 + 1] = (_Float16)v.y;
        tile[row][col * 4 + 2] = (_Float16)v.z;
        tile[row][col * 4 + 3] = (_Float16)v.w;
    }
    __syncthreads();
    // Vt[b][a=qq][d=t][j]: halves offset b*8192 + a*2048 + t*8
    _Float16* dst = Vt + (size_t)b * 8192 + (size_t)t * 8;
    #pragma unroll
    for (int a = 0; a < 4; ++a) {
        h8 w;
        #pragma unroll
        for (int j = 0; j < 4; ++j) {
            w[j]     = tile[4 * a + j][t];          // pi(8a+j), j<4
            w[4 + j] = tile[16 + 4 * a + j][t];     // pi(8a+4+j)
        }
        *(h8_a*)(dst + (size_t)a * 2048) = w;
    }
}

// ---------------- main attention kernel ----------------------------------
__device__ __forceinline__ void gl16(const void* g, void* l) {
    __builtin_amdgcn_global_load_lds(
        (const __attribute__((address_space(1))) void*)g,
        (__attribute__((address_space(3))) void*)l, 16, 0, 0);
}

__device__ __forceinline__ h2 pkrtz(float a, float b) {
    h2raw r = __builtin_amdgcn_cvt_pkrtz(a, b);
    return __builtin_bit_cast(h2, r);
}

// K@Q^T for one 32-key tile: 8 contiguous-b128 K-frag reads, 32 fp8 MFMAs.
__device__ __forceinline__ void qk32(const unsigned char* kb, int koff,
                                     const long (&qf)[2][8], f32x4 (&sc)[2][2]) {
    #pragma unroll
    for (int h = 0; h < 2; ++h)
        #pragma unroll
        for (int t = 0; t < 2; ++t) sc[h][t] = (f32x4){0.f, 0.f, 0.f, 0.f};
    #pragma unroll
    for (int s16 = 0; s16 < 4; ++s16) {
        #pragma unroll
        for (int h = 0; h < 2; ++h) {
            lx2 kp = *(const lx2_a*)(kb + (s16 * 2 + h) * 1024 + koff);
            #pragma unroll
            for (int t = 0; t < 2; ++t) {
                sc[h][t] = __builtin_amdgcn_mfma_f32_16x16x32_fp8_fp8(kp[0], qf[t][2 * s16],     sc[h][t], 0, 0, 0);
                sc[h][t] = __builtin_amdgcn_mfma_f32_16x16x32_fp8_fp8(kp[1], qf[t][2 * s16 + 1], sc[h][t], 0, 0, 0);
            }
        }
    }
}

#define STAGE(KG, VG, BUF)                                                   \
    do {                                                                     \
        gl16((KG) + tid * 16,           (BUF) + wb);                         \
        gl16((KG) + 4096 + tid * 16,    (BUF) + 4096 + wb);                  \
        gl16((VG) + tid * 16,           (BUF) + KTILE + wb);                 \
        gl16((VG) + 4096 + tid * 16,    (BUF) + KTILE + 4096 + wb);         \
        gl16((VG) + 8192 + tid * 16,    (BUF) + KTILE + 8192 + wb);         \
        gl16((VG) + 12288 + tid * 16,   (BUF) + KTILE + 12288 + wb);        \
    } while (0)

// grid = 64 q-tiles x 8 splits, 256 threads (4 waves x 32 q-rows).
__global__ void __launch_bounds__(256, 2)
attn(const unsigned char* __restrict__ Q8, const unsigned char* __restrict__ K8,
     const _Float16* __restrict__ Vt, _Float16* __restrict__ Op,
     float* __restrict__ lp) {
    // 3 buffers x (8KB K + 16KB V) = 72KB -> 2 blocks/CU
    __shared__ __align__(16) unsigned char lds[3 * BUFSZ];

    int tid = threadIdx.x;
    int wid = tid >> 6, lane = tid & 63;
    int l15 = lane & 15, qq = lane >> 4;
    int wb = wid << 10;                           // wave-uniform LDS sub-base
    int qt_blk = blockIdx.x >> 3, sp = blockIdx.x & 7;
    int qrow0 = qt_blk * BM + wid * 32;

    // Q fp8 B-frags (S^T: B[n=q=l15][k=s*32+qq*8+j]) straight from global
    long qf[2][8];
    #pragma unroll
    for (int t = 0; t < 2; ++t) {
        const unsigned char* p = Q8 + (size_t)(qrow0 + t * 16 + l15) * DIM + qq * 8;
        #pragma unroll
        for (int s = 0; s < 8; ++s) qf[t][s] = *(const long_a*)(p + s * 32);
    }

    // ones B-frag (f16, K=32) for l = P @ ones: B[n][k] = (n==0)
    _Float16 one = (l15 == 0) ? (_Float16)1.0f : (_Float16)0.0f;
    h8 of = {one, one, one, one, one, one, one, one};

    unsigned char* bufA = lds;                    // tile it   (PV source)
    unsigned char* bufB = lds + BUFSZ;            // tile it+1 (QK source)
    unsigned char* bufC = lds + 2 * BUFSZ;        // tile it+2 (stage target)

    const unsigned char* kg = K8 + (size_t)sp * ITERS * KTILE;
    const unsigned char* vg = (const unsigned char*)Vt + (size_t)sp * ITERS * VTILE;

    f32x4 acc[2][16] = {};
    f32x4 accl[2] = {};

    int koff = qq * 256 + l15 * 16;
    int voff = qq * 4096 + l15 * 16;

    // prologue: stage tiles 0,1; QK(0)
    STAGE(kg, vg, bufA); kg += KTILE; vg += VTILE;
    STAGE(kg, vg, bufB); kg += KTILE; vg += VTILE;
    __syncthreads();                               // drains vmcnt(0)
    f32x4 sc_p[2][2];
    qk32(bufA, koff, qf, sc_p);

    for (int it = 0; it < ITERS; ++it) {
        // stage tile it+2 into bufC: last reader of bufC (PV(it-1)) finished
        // before the barrier that precedes this body -> DMA is race-free and
        // overlaps the whole body; end-of-body __syncthreads drains it.
        if (it + 2 < ITERS) { STAGE(kg, vg, bufC); kg += KTILE; vg += VTILE; }

        __builtin_amdgcn_s_setprio(1);

        // QK(it+1) -- independent of exp2(it), fills the MFMA pipe under it
        f32x4 sc_n[2][2] = {};
        if (it + 1 < ITERS) qk32(bufB, koff, qf, sc_n);

        // P(it) = exp2(min(S*KSC,16)) on sc from the PREVIOUS body (settled);
        // pkrtz pack: RTZ bias cancels in P/sum(P) since l uses same values.
        h8 pfrag[2];
        #pragma unroll
        for (int t = 0; t < 2; ++t) {
            float e0 = __builtin_amdgcn_exp2f(fminf(sc_p[0][t][0] * KSC, 16.0f));
            float e1 = __builtin_amdgcn_exp2f(fminf(sc_p[0][t][1] * KSC, 16.0f));
            float e2 = __builtin_amdgcn_exp2f(fminf(sc_p[0][t][2] * KSC, 16.0f));
            float e3 = __builtin_amdgcn_exp2f(fminf(sc_p[0][t][3] * KSC, 16.0f));
            float e4 = __builtin_amdgcn_exp2f(fminf(sc_p[1][t][0] * KSC, 16.0f));
            float e5 = __builtin_amdgcn_exp2f(fminf(sc_p[1][t][1] * KSC, 16.0f));
            float e6 = __builtin_amdgcn_exp2f(fminf(sc_p[1][t][2] * KSC, 16.0f));
            float e7 = __builtin_amdgcn_exp2f(fminf(sc_p[1][t][3] * KSC, 16.0f));
            h2 p01 = pkrtz(e0, e1);
            h2 p23 = pkrtz(e2, e3);
            h2 p45 = pkrtz(e4, e5);
            h2 p67 = pkrtz(e6, e7);
            h8 pf;
            pf[0] = p01[0]; pf[1] = p01[1]; pf[2] = p23[0]; pf[3] = p23[1];
            pf[4] = p45[0]; pf[5] = p45[1]; pf[6] = p67[0]; pf[7] = p67[1];
            pfrag[t] = pf;
        }

        // O += P @ V : contiguous-b128 vf reads, pfrag ready
        const unsigned char* vb = bufA + KTILE + voff;
        #pragma unroll
        for (int n = 0; n < 16; ++n) {
            h8 vf = *(const h8_a*)(vb + n * 256);
            acc[0][n] = __builtin_amdgcn_mfma_f32_16x16x32_f16(pfrag[0], vf, acc[0][n], 0, 0, 0);
            acc[1][n] = __builtin_amdgcn_mfma_f32_16x16x32_f16(pfrag[1], vf, acc[1][n], 0, 0, 0);
        }
        accl[0] = __builtin_amdgcn_mfma_f32_16x16x32_f16(pfrag[0], of, accl[0], 0, 0, 0);
        accl[1] = __builtin_amdgcn_mfma_f32_16x16x32_f16(pfrag[1], of, accl[1], 0, 0, 0);

        __builtin_amdgcn_s_setprio(0);
        __syncthreads();                           // vmcnt(0) drain + barrier

        // rotate buffers + score state
        unsigned char* tb = bufA; bufA = bufB; bufB = bufC; bufC = tb;
        #pragma unroll
        for (int h = 0; h < 2; ++h)
            #pragma unroll
            for (int t = 0; t < 2; ++t) sc_p[h][t] = sc_n[h][t];
    }

    // epilogue: f16 O partials + fp32 l partials
    #pragma unroll
    for (int t = 0; t < 2; ++t) {
        #pragma unroll
        for (int n = 0; n < 16; ++n)
            #pragma unroll
            for (int r = 0; r < 4; ++r) {
                int row = qrow0 + t * 16 + qq * 4 + r;
                Op[((size_t)sp * SEQ + row) * DIM + n * 16 + l15] = (_Float16)acc[t][n][r];
            }
        if (l15 == 0) {
            #pragma unroll
            for (int r = 0; r < 4; ++r)
                lp[(size_t)sp * SEQ + qrow0 + t * 16 + qq * 4 + r] = accl[t][r];
        }
    }
}

// ---------------- combine: out = sum_s(Op_s) / sum_s(lp_s) ----------------
__global__ void __launch_bounds__(256)
combine(const _Float16* __restrict__ Op, const float* __restrict__ lp,
        float* __restrict__ out) {
    int idx = blockIdx.x * 256 + threadIdx.x;   // h8 chunk, 262144 total
    int row = idx >> 5;
    f32x4 a0 = {}, a1 = {};
    float l = 0.0f;
    #pragma unroll
    for (int s = 0; s < NSPLIT; ++s) {
        h8 h = *(const h8_a*)(Op + (size_t)s * SEQ * DIM + (size_t)idx * 8);
        a0.x += (float)h[0]; a0.y += (float)h[1];
        a0.z += (float)h[2]; a0.w += (float)h[3];
        a1.x += (float)h[4]; a1.y += (float)h[5];
        a1.z += (float)h[6]; a1.w += (float)h[7];
        l += lp[s * SEQ + row];
    }
    float linv = 1.0f / (l + 1e-20f);
    ((f32x4*)out)[idx * 2]     = a0 * linv;
    ((f32x4*)out)[idx * 2 + 1] = a1 * linv;
}

extern "C" void kernel_launch(void* const* d_in, const int* in_sizes, int n_in,
                              void* d_out, int out_size, void* d_ws, size_t ws_size,
                              hipStream_t stream) {
    const float* Q = (const float*)d_in[0];
    const float* K = (const float*)d_in[1];
    const float* V = (const float*)d_in[2];
    float* out = (float*)d_out;

    char* ws = (char*)d_ws;
    unsigned char* Q8 = (unsigned char*)ws;                // 2 MB fp8 row-major
    unsigned char* K8 = (unsigned char*)(ws + (2u << 20)); // 2 MB fp8 LDS-image tiles
    _Float16* Vt = (_Float16*)(ws + (4u << 20));           // 4 MB f16 [tile][qq][d][8k]
    _Float16* Op = (_Float16*)(ws + (8u << 20));           // 32 MB f16 partials
    float*    lp = (float*)(ws + (40u << 20));             // 256 KB

    prep   <<<256, 256, 0, stream>>>(Q, K, V, Q8, K8, Vt);
    attn   <<<NSPLIT * (SEQ / BM), 256, 0, stream>>>(Q8, K8, Vt, Op, lp);
    combine<<<1024, 256, 0, stream>>>(Op, lp, out);
}